// Round 6
// baseline (101.196 us; speedup 1.0000x reference)
//
#include <hip/hip_runtime.h>
#include <hip/hip_bf16.h>
#include <hip/hip_cooperative_groups.h>

#define NN 2048
#define DD 128

namespace cg = cooperative_groups;

typedef __attribute__((ext_vector_type(4))) float f32x4;
typedef __attribute__((ext_vector_type(8))) short short8;
typedef __attribute__((ext_vector_type(2))) unsigned int u32x2;

__device__ __forceinline__ unsigned short f2bf_bits(float f) {
  union { __hip_bfloat16 h; unsigned short s; } u;
  u.h = __float2bfloat16(f);
  return u.s;
}

__device__ __forceinline__ short8 cvt8(f32x4 a, f32x4 b) {
  short8 r;
  r[0] = (short)f2bf_bits(a[0]); r[1] = (short)f2bf_bits(a[1]);
  r[2] = (short)f2bf_bits(a[2]); r[3] = (short)f2bf_bits(a[3]);
  r[4] = (short)f2bf_bits(b[0]); r[5] = (short)f2bf_bits(b[1]);
  r[6] = (short)f2bf_bits(b[2]); r[7] = (short)f2bf_bits(b[3]);
  return r;
}

__device__ __forceinline__ u32x2 pack4(f32x4 v) {
  u32x2 u;
  u[0] = (unsigned)f2bf_bits(v[0]) | ((unsigned)f2bf_bits(v[1]) << 16);
  u[1] = (unsigned)f2bf_bits(v[2]) | ((unsigned)f2bf_bits(v[3]) << 16);
  return u;
}

// ===================== single-pass cooperative kernel =====================
// 256 blocks x 512 thr (1 block/CU). Block owns 64 adj rows.
// P1: stream rows from HBM once -> rowsum (dnl in LDS) + bf16 stash
//     (k<1024 -> padded LDS, k>=1024 -> 64 VGPR/thread, static idx).
// P1.5: yT[d][n] = bf16(dnl[n]*(x@W)[n][d]) for own 64 n. grid.sync.
// P2: out = (rows @ y)*dnl + b. LDS tiles + reg tiles via ping-pong dbuf.
// LDS layout: PADDED rows (+16B) instead of XOR swizzle — r5's bug was a
// non-closed XOR (mask bit 6 overlapped the un-XOR'd T*64 term). Padding
// makes write/read trivially the same linear map; row*16 bank rotation
// keeps ds_read_b128 at 2-way (= free, m136).
#define ABIG_S 1032   // shorts per Abig row (2064 B, 16B-aligned)
#define DBUF_S 72     // shorts per dbuf row (144 B, 16B-aligned)
__launch_bounds__(512, 2)
__global__ void k_fused(const float* __restrict__ adj, const float* __restrict__ x,
                        const float* __restrict__ W, const float* __restrict__ bias,
                        float* __restrict__ out, short* __restrict__ yT) {
  __shared__ short Abig[64 * ABIG_S];   // 129 KB
  __shared__ short dbuf[2][64 * DBUF_S]; // 18 KB ping-pong
  __shared__ float dnl[64];

  const int t = threadIdx.x;
  const int ln = t & 63;
  const int wv = t >> 6;
  const int l15 = ln & 15, l4 = ln >> 4;

  // XCD-bijective swizzle: XCD x owns batch x (yT slice L2-local)
  const int orig = ((blockIdx.x & 7) << 5) | (blockIdx.x >> 3);
  const int bb = orig >> 5;
  const int rowblk = orig & 31;
  const size_t rowg0 = (size_t)bb * NN + (rowblk << 6);

  // ---- phase 1 ----
  const int r = t >> 3, c8 = t & 7;   // 8 threads per row, 64 rows
  const float* arow = adj + (rowg0 + r) * NN + (c8 << 2);
  char* awr = (char*)Abig + r * (ABIG_S * 2) + (c8 << 3);  // linear

  float s0 = 0.f, s1 = 0.f;
  u32x2 areg[32];
#pragma unroll
  for (int T = 0; T < 32; ++T) {
    f32x4 v = *(const f32x4*)(arow + T * 32);
    s0 += v[0] + v[1]; s1 += v[2] + v[3];
    *(u32x2*)(awr + T * 64) = pack4(v);
  }
#pragma unroll
  for (int T = 0; T < 32; ++T) {
    f32x4 v = *(const f32x4*)(arow + (32 + T) * 32);
    s0 += v[0] + v[1]; s1 += v[2] + v[3];
    areg[T] = pack4(v);
  }
  float s = s0 + s1;
  s += __shfl_xor(s, 1); s += __shfl_xor(s, 2); s += __shfl_xor(s, 4);
  if (c8 == 0) dnl[r] = rsqrtf(s + 1e-8f);
  __syncthreads();

  // ---- phase 1.5: yT for own 64 n-rows ----
  {
    const int nch = rowblk << 6;
    const int dbase = (wv & 3) << 5;
    const int nh = (wv >> 2) << 5;
    short8 af[2][4];
#pragma unroll
    for (int dt = 0; dt < 2; ++dt)
#pragma unroll
      for (int ks = 0; ks < 4; ++ks) {
        short8 a;
#pragma unroll
        for (int j = 0; j < 8; ++j)
          a[j] = (short)f2bf_bits(W[(size_t)(ks * 32 + l4 * 8 + j) * DD + dbase + dt * 16 + l15]);
        af[dt][ks] = a;
      }
    f32x4 acc2[2][2];
    acc2[0][0] = (f32x4)0.f; acc2[0][1] = (f32x4)0.f;
    acc2[1][0] = (f32x4)0.f; acc2[1][1] = (f32x4)0.f;
#pragma unroll
    for (int nt = 0; nt < 2; ++nt) {
      const int nloc = nh + nt * 16 + l15;
      const float dn = dnl[nloc];
      const float* xr = x + ((size_t)bb * NN + nch + nloc) * DD;
#pragma unroll
      for (int ks = 0; ks < 4; ++ks) {
        f32x4 p = *(const f32x4*)(xr + ks * 32 + l4 * 8);
        f32x4 q = *(const f32x4*)(xr + ks * 32 + l4 * 8 + 4);
        short8 bf = cvt8(p * dn, q * dn);
        acc2[0][nt] = __builtin_amdgcn_mfma_f32_16x16x32_bf16(af[0][ks], bf, acc2[0][nt], 0, 0, 0);
        acc2[1][nt] = __builtin_amdgcn_mfma_f32_16x16x32_bf16(af[1][ks], bf, acc2[1][nt], 0, 0, 0);
      }
    }
    short* yb = yT + (size_t)bb * DD * NN;
#pragma unroll
    for (int dt = 0; dt < 2; ++dt)
#pragma unroll
      for (int nt = 0; nt < 2; ++nt)
#pragma unroll
        for (int rr = 0; rr < 4; ++rr)
          yb[(size_t)(dbase + dt * 16 + l4 * 4 + rr) * NN + nch + nh + nt * 16 + l15] =
              (short)f2bf_bits(acc2[dt][nt][rr]);
  }

  cg::this_grid().sync();

  // ---- phase 2 ----
  const int oc = (wv << 4) + l15;
  const int kg8 = l4 << 3;
  const short* ybase = yT + ((size_t)bb * DD + oc) * NN;
  char* dwr = (char*)dbuf + r * (DBUF_S * 2) + (c8 << 3);  // linear

  f32x4 acc[4];
#pragma unroll
  for (int m = 0; m < 4; ++m) acc[m] = (f32x4)0.f;

  auto loadB = [&](int kt, int ks) -> short8 {
    return *(const short8*)(ybase + (kt << 6) + ks * 32 + kg8);
  };
  auto ctile = [&](const char* tb, unsigned rstride, short8 b0, short8 b1) {
#pragma unroll
    for (int ks = 0; ks < 2; ++ks) {
      short8 bf = ks ? b1 : b0;
#pragma unroll
      for (int m = 0; m < 4; ++m) {
        unsigned row = (unsigned)(m * 16 + l15);
        unsigned byte = row * rstride + (unsigned)((ks * 32 + kg8) << 1);
        short8 a = *(const short8*)(tb + byte);
        acc[m] = __builtin_amdgcn_mfma_f32_16x16x32_bf16(a, bf, acc[m], 0, 0, 0);
      }
    }
  };

  // prologue: reg-tile 0 -> dbuf0; B frags for LDS-tile 0 and reg-tile 16
  *(u32x2*)dwr = areg[0];
  *(u32x2*)(dwr + 64) = areg[1];
  short8 bA0 = loadB(0, 0), bA1 = loadB(0, 1);
  short8 bD0 = loadB(16, 0), bD1 = loadB(16, 1);
  asm volatile("s_waitcnt lgkmcnt(0)\n\ts_barrier" ::: "memory");

#pragma unroll
  for (int j = 0; j < 16; ++j) {
    if (j < 15) {
      *(u32x2*)(dwr + ((j + 1) & 1) * (64 * DBUF_S * 2)) = areg[2 * j + 2];
      *(u32x2*)(dwr + ((j + 1) & 1) * (64 * DBUF_S * 2) + 64) = areg[2 * j + 3];
    }
    short8 nA0 = bA0, nA1 = bA1, nD0 = bD0, nD1 = bD1;
    if (j < 15) {
      nA0 = loadB(j + 1, 0); nA1 = loadB(j + 1, 1);
      nD0 = loadB(17 + j, 0); nD1 = loadB(17 + j, 1);
    }
    ctile((const char*)Abig + j * 128, (unsigned)(ABIG_S * 2), bA0, bA1);       // k-tile j
    ctile((const char*)dbuf + (j & 1) * (64 * DBUF_S * 2), (unsigned)(DBUF_S * 2), bD0, bD1);  // k-tile 16+j
    asm volatile("s_waitcnt lgkmcnt(0)\n\ts_barrier" ::: "memory");
    bA0 = nA0; bA1 = nA1; bD0 = nD0; bD1 = nD1;
  }

  const float bv = bias[oc];
  const int rb = l4 << 2;
#pragma unroll
  for (int m = 0; m < 4; ++m)
#pragma unroll
    for (int rr = 0; rr < 4; ++rr) {
      const int row = m * 16 + rb + rr;
      out[(rowg0 + row) * DD + oc] = acc[m][rr] * dnl[row] + bv;
    }
}

// ===================== fallback path (round-3, proven 69 µs) =====================
__global__ void k_degree(const float* __restrict__ adj, float* __restrict__ dnorm) {
  const int wv = threadIdx.x >> 6;
  const int ln = threadIdx.x & 63;
  const int row = blockIdx.x * 4 + wv;
  const f32x4* rowp = (const f32x4*)(adj + (size_t)row * NN);
  float s = 0.0f;
#pragma unroll
  for (int i = 0; i < 8; ++i) {
    f32x4 v = rowp[i * 64 + ln];
    s += v[0] + v[1] + v[2] + v[3];
  }
#pragma unroll
  for (int off = 32; off >= 1; off >>= 1) s += __shfl_xor(s, off);
  if (ln == 0) dnorm[row] = rsqrtf(s + 1e-8f);
}

__global__ void k_y(const float* __restrict__ x, const float* __restrict__ W,
                    const float* __restrict__ dnorm, short* __restrict__ yT) {
  const int ln = threadIdx.x & 63;
  const int wv = threadIdx.x >> 6;
  const int bb = blockIdx.x >> 5;
  const int n0 = (blockIdx.x & 31) << 6;
  const int l15 = ln & 15, l4 = ln >> 4;
  const int dbase = wv * 32;

  short8 af[2][4];
#pragma unroll
  for (int dt = 0; dt < 2; ++dt)
#pragma unroll
    for (int ks = 0; ks < 4; ++ks) {
      short8 a;
#pragma unroll
      for (int j = 0; j < 8; ++j)
        a[j] = (short)f2bf_bits(W[(size_t)(ks * 32 + l4 * 8 + j) * DD + dbase + dt * 16 + l15]);
      af[dt][ks] = a;
    }

  f32x4 acc[2][4];
#pragma unroll
  for (int dt = 0; dt < 2; ++dt)
#pragma unroll
    for (int nt = 0; nt < 4; ++nt) acc[dt][nt] = (f32x4)0.0f;

  const float* xb = x + (size_t)bb * NN * DD;
  const float* dnb = dnorm + (size_t)bb * NN;
#pragma unroll
  for (int nt = 0; nt < 4; ++nt) {
    const int n = n0 + nt * 16 + l15;
    const float dn = dnb[n];
#pragma unroll
    for (int ks = 0; ks < 4; ++ks) {
      f32x4 p = *(const f32x4*)(xb + (size_t)n * DD + ks * 32 + l4 * 8);
      f32x4 q = *(const f32x4*)(xb + (size_t)n * DD + ks * 32 + l4 * 8 + 4);
      short8 bf = cvt8(p * dn, q * dn);
#pragma unroll
      for (int dt = 0; dt < 2; ++dt)
        acc[dt][nt] = __builtin_amdgcn_mfma_f32_16x16x32_bf16(af[dt][ks], bf, acc[dt][nt], 0, 0, 0);
    }
  }

  short* yb = yT + (size_t)bb * DD * NN;
#pragma unroll
  for (int dt = 0; dt < 2; ++dt)
#pragma unroll
    for (int nt = 0; nt < 4; ++nt)
#pragma unroll
      for (int rr = 0; rr < 4; ++rr) {
        int d = dbase + dt * 16 + l4 * 4 + rr;
        yb[(size_t)d * NN + n0 + nt * 16 + l15] = (short)f2bf_bits(acc[dt][nt][rr]);
      }
}

__launch_bounds__(512, 4)
__global__ void k_gemm(const float* __restrict__ adj, const short* __restrict__ yT,
                       const float* __restrict__ dnorm, const float* __restrict__ bias,
                       float* __restrict__ out) {
  __shared__ short As[4][2048];

  const int t = threadIdx.x;
  const int ln = t & 63;
  const int wv = t >> 6;
  const int orig = ((blockIdx.x & 7) << 6) | (blockIdx.x >> 3);
  const int bb = orig >> 6;
  const int m0 = (orig & 63) << 5;

  const float* ablk = adj + ((size_t)bb * NN + m0) * NN;
  const int oc = (wv << 4) + (ln & 15);
  const int kg8 = (ln >> 4) << 3;
  const short* ybase = yT + ((size_t)bb * DD + oc) * NN;

  const unsigned srow = (unsigned)t >> 4;
  const unsigned sc4 = ((unsigned)t & 15u) << 2;

  f32x4 acc[2];
  acc[0] = (f32x4)0.0f; acc[1] = (f32x4)0.0f;

  auto loadA = [&](int tile) -> f32x4 {
    return *(const f32x4*)(ablk + (size_t)srow * NN + ((tile & 31) << 6) + sc4);
  };
  auto loadB = [&](int tile, int ks) -> short8 {
    return *(const short8*)(ybase + ((tile & 31) << 6) + ks * 32 + kg8);
  };
  auto writeA = [&](f32x4 v, int buf) {
    unsigned byte = (srow << 7) + (sc4 << 1);
    byte ^= (srow & 7u) << 4;
    *(u32x2*)((char*)As + (buf << 12) + byte) = pack4(v);
  };
  auto compute = [&](int buf, short8 b0, short8 b1) {
    const char* base = (const char*)As + (buf << 12);
#pragma unroll
    for (int ks = 0; ks < 2; ++ks) {
      short8 bf = ks ? b1 : b0;
#pragma unroll
      for (int m = 0; m < 2; ++m) {
        unsigned row = (unsigned)(m * 16 + (ln & 15));
        unsigned byte = (row << 7) + (unsigned)((ks * 32 + kg8) << 1);
        byte ^= (row & 7u) << 4;
        short8 a = *(const short8*)(base + byte);
        acc[m] = __builtin_amdgcn_mfma_f32_16x16x32_bf16(a, bf, acc[m], 0, 0, 0);
      }
    }
  };

  f32x4 sA0 = loadA(0), sA1 = loadA(1), sA2 = loadA(2), sA3 = loadA(3);
  short8 bE0 = loadB(0, 0), bE1 = loadB(0, 1);
  short8 bO0 = loadB(1, 0), bO1 = loadB(1, 1);
  writeA(sA0, 0);
  asm volatile("s_waitcnt lgkmcnt(0)\n\ts_barrier" ::: "memory");

#define GITER(T, SNEW, SWR, BC0, BC1)                                 \
  {                                                                   \
    SNEW = loadA((T) + 4);                                            \
    short8 nb0 = loadB((T) + 2, 0), nb1 = loadB((T) + 2, 1);          \
    writeA(SWR, ((T) + 1) & 3);                                       \
    asm volatile("s_waitcnt lgkmcnt(0)\n\ts_barrier" ::: "memory");   \
    compute((T) & 3, BC0, BC1);                                       \
    BC0 = nb0; BC1 = nb1;                                             \
  }

#pragma unroll 1
  for (int t4 = 0; t4 < 32; t4 += 4) {
    GITER(t4 + 0, sA0, sA1, bE0, bE1);
    GITER(t4 + 1, sA1, sA2, bO0, bO1);
    GITER(t4 + 2, sA2, sA3, bE0, bE1);
    GITER(t4 + 3, sA3, sA0, bO0, bO1);
  }
#undef GITER

  const float bv = bias[oc];
  const int rbase = (ln >> 4) << 2;
#pragma unroll
  for (int m = 0; m < 2; ++m) {
    f32x4 dn = *(const f32x4*)(dnorm + (size_t)bb * NN + m0 + m * 16 + rbase);
#pragma unroll
    for (int rr = 0; rr < 4; ++rr)
      out[(size_t)(bb * NN + m0 + m * 16 + rbase + rr) * DD + oc] = acc[m][rr] * dn[rr] + bv;
  }
}

extern "C" void kernel_launch(void* const* d_in, const int* in_sizes, int n_in,
                              void* d_out, int out_size, void* d_ws, size_t ws_size,
                              hipStream_t stream) {
  (void)in_sizes; (void)n_in; (void)out_size; (void)ws_size;
  const float* x = (const float*)d_in[0];
  const float* adj = (const float*)d_in[1];
  const float* W = (const float*)d_in[2];
  const float* bias = (const float*)d_in[3];
  float* out = (float*)d_out;

  char* ws = (char*)d_ws;
  float* dnorm = (float*)ws;             // 64 KB (fallback only)
  short* yT = (short*)(ws + (1 << 16));  // 4 MB

  void* args[] = {(void*)&adj, (void*)&x, (void*)&W, (void*)&bias,
                  (void*)&out, (void*)&yT};
  hipError_t e = hipLaunchCooperativeKernel((const void*)k_fused, dim3(256),
                                            dim3(512), args, 0, stream);
  if (e != hipSuccess) {
    (void)hipGetLastError();  // clear sticky error, take proven 3-kernel path
    k_degree<<<4096, 256, 0, stream>>>(adj, dnorm);
    k_y<<<256, 256, 0, stream>>>(x, W, dnorm, yT);
    k_gemm<<<512, 512, 0, stream>>>(adj, yT, dnorm, bias, out);
  }
}

// Round 7
// 67.876 us; speedup vs baseline: 1.4909x; 1.4909x over previous
//
#include <hip/hip_runtime.h>
#include <hip/hip_bf16.h>

#define NN 2048
#define DD 128

typedef __attribute__((ext_vector_type(4))) float f32x4;
typedef __attribute__((ext_vector_type(8))) short short8;
typedef __attribute__((ext_vector_type(2))) unsigned int u32x2;

__device__ __forceinline__ unsigned short f2bf_bits(float f) {
  union { __hip_bfloat16 h; unsigned short s; } u;
  u.h = __float2bfloat16(f);
  return u.s;
}

__device__ __forceinline__ short8 cvt8(f32x4 a, f32x4 b) {
  short8 r;
  r[0] = (short)f2bf_bits(a[0]); r[1] = (short)f2bf_bits(a[1]);
  r[2] = (short)f2bf_bits(a[2]); r[3] = (short)f2bf_bits(a[3]);
  r[4] = (short)f2bf_bits(b[0]); r[5] = (short)f2bf_bits(b[1]);
  r[6] = (short)f2bf_bits(b[2]); r[7] = (short)f2bf_bits(b[3]);
  return r;
}

__device__ __forceinline__ u32x2 pack4(f32x4 v) {
  u32x2 u;
  u[0] = (unsigned)f2bf_bits(v[0]) | ((unsigned)f2bf_bits(v[1]) << 16);
  u[1] = (unsigned)f2bf_bits(v[2]) | ((unsigned)f2bf_bits(v[3]) << 16);
  return u;
}

// ---------- K1: dnorm = rsqrt(rowsum(adj)+1e-8) ----------
__global__ void k_degree(const float* __restrict__ adj, float* __restrict__ dnorm) {
  const int wv = threadIdx.x >> 6;
  const int ln = threadIdx.x & 63;
  const int row = blockIdx.x * 4 + wv;
  const f32x4* rowp = (const f32x4*)(adj + (size_t)row * NN);
  float s = 0.0f;
#pragma unroll
  for (int i = 0; i < 8; ++i) {
    f32x4 v = rowp[i * 64 + ln];
    s += v[0] + v[1] + v[2] + v[3];
  }
#pragma unroll
  for (int off = 32; off >= 1; off >>= 1) s += __shfl_xor(s, off);
  if (ln == 0) dnorm[row] = rsqrtf(s + 1e-8f);
}

// ---------- K2: yT[b][d][n] = bf16(dnorm[n] * (x@W)[n][d]) ----------
__global__ void k_y(const float* __restrict__ x, const float* __restrict__ W,
                    const float* __restrict__ dnorm, short* __restrict__ yT) {
  const int ln = threadIdx.x & 63;
  const int wv = threadIdx.x >> 6;
  const int bb = blockIdx.x >> 5;
  const int n0 = (blockIdx.x & 31) << 6;
  const int l15 = ln & 15, l4 = ln >> 4;
  const int dbase = wv * 32;

  short8 af[2][4];
#pragma unroll
  for (int dt = 0; dt < 2; ++dt)
#pragma unroll
    for (int ks = 0; ks < 4; ++ks) {
      short8 a;
#pragma unroll
      for (int j = 0; j < 8; ++j)
        a[j] = (short)f2bf_bits(W[(size_t)(ks * 32 + l4 * 8 + j) * DD + dbase + dt * 16 + l15]);
      af[dt][ks] = a;
    }

  f32x4 acc[2][4];
#pragma unroll
  for (int dt = 0; dt < 2; ++dt)
#pragma unroll
    for (int nt = 0; nt < 4; ++nt) acc[dt][nt] = (f32x4)0.0f;

  const float* xb = x + (size_t)bb * NN * DD;
  const float* dnb = dnorm + (size_t)bb * NN;
#pragma unroll
  for (int nt = 0; nt < 4; ++nt) {
    const int n = n0 + nt * 16 + l15;
    const float dn = dnb[n];
#pragma unroll
    for (int ks = 0; ks < 4; ++ks) {
      f32x4 p = *(const f32x4*)(xb + (size_t)n * DD + ks * 32 + l4 * 8);
      f32x4 q = *(const f32x4*)(xb + (size_t)n * DD + ks * 32 + l4 * 8 + 4);
      short8 bf = cvt8(p * dn, q * dn);
#pragma unroll
      for (int dt = 0; dt < 2; ++dt)
        acc[dt][nt] = __builtin_amdgcn_mfma_f32_16x16x32_bf16(af[dt][ks], bf, acc[dt][nt], 0, 0, 0);
    }
  }

  short* yb = yT + (size_t)bb * DD * NN;
#pragma unroll
  for (int dt = 0; dt < 2; ++dt)
#pragma unroll
    for (int nt = 0; nt < 4; ++nt)
#pragma unroll
      for (int rr = 0; rr < 4; ++rr) {
        int d = dbase + dt * 16 + l4 * 4 + rr;
        yb[(size_t)d * NN + n0 + nt * 16 + l15] = (short)f2bf_bits(acc[dt][nt][rr]);
      }
}

// ---------- K3: out[n][:] = dnorm[n] * (adj[n,:] @ y) + b ----------
// Round-3 structure, deeper pipeline: A depth-8 (regs), B depth-4 (regs),
// NBUF=4 LDS ring, one lgkmcnt(0)+barrier per K-tile. Static rotation only.
__launch_bounds__(512, 4)
__global__ void k_gemm(const float* __restrict__ adj, const short* __restrict__ yT,
                       const float* __restrict__ dnorm, const float* __restrict__ bias,
                       float* __restrict__ out) {
  __shared__ short As[4][2048];  // 4 x 4 KB: [32 rows][64 k] bf16

  const int t = threadIdx.x;
  const int ln = t & 63;
  const int wv = t >> 6;
  const int orig = ((blockIdx.x & 7) << 6) | (blockIdx.x >> 3);  // XCD-bijective
  const int bb = orig >> 6;
  const int m0 = (orig & 63) << 5;

  const float* ablk = adj + ((size_t)bb * NN + m0) * NN;
  const int oc = (wv << 4) + (ln & 15);
  const int kg8 = (ln >> 4) << 3;
  const short* ybase = yT + ((size_t)bb * DD + oc) * NN;

  const unsigned srow = (unsigned)t >> 4;
  const unsigned sc4 = ((unsigned)t & 15u) << 2;

  f32x4 acc[2];
  acc[0] = (f32x4)0.0f; acc[1] = (f32x4)0.0f;

  auto loadA = [&](int tile) -> f32x4 {
    return *(const f32x4*)(ablk + (size_t)srow * NN + (tile << 6) + sc4);
  };
  auto loadB = [&](int tile, int ks) -> short8 {
    return *(const short8*)(ybase + (tile << 6) + ks * 32 + kg8);
  };
  auto writeA = [&](f32x4 v, int buf) {
    unsigned byte = (srow << 7) + (sc4 << 1);
    byte ^= (srow & 7u) << 4;
    *(u32x2*)((char*)As + (buf << 12) + byte) = pack4(v);
  };
  auto compute = [&](int buf, short8 b0, short8 b1) {
    const char* base = (const char*)As + (buf << 12);
#pragma unroll
    for (int ks = 0; ks < 2; ++ks) {
      short8 bf = ks ? b1 : b0;
#pragma unroll
      for (int m = 0; m < 2; ++m) {
        unsigned row = (unsigned)(m * 16 + (ln & 15));
        unsigned byte = (row << 7) + (unsigned)((ks * 32 + kg8) << 1);
        byte ^= (row & 7u) << 4;
        short8 a = *(const short8*)(base + byte);
        acc[m] = __builtin_amdgcn_mfma_f32_16x16x32_bf16(a, bf, acc[m], 0, 0, 0);
      }
    }
  };

  // prologue: A tiles 0..7 in regs, B tiles 0..3 in regs, tile 0 -> LDS buf0
  f32x4 sA0 = loadA(0), sA1 = loadA(1), sA2 = loadA(2), sA3 = loadA(3);
  f32x4 sA4 = loadA(4), sA5 = loadA(5), sA6 = loadA(6), sA7 = loadA(7);
  short8 b0k0 = loadB(0, 0), b0k1 = loadB(0, 1);
  short8 b1k0 = loadB(1, 0), b1k1 = loadB(1, 1);
  short8 b2k0 = loadB(2, 0), b2k1 = loadB(2, 1);
  short8 b3k0 = loadB(3, 0), b3k1 = loadB(3, 1);
  writeA(sA0, 0);
  asm volatile("s_waitcnt lgkmcnt(0)\n\ts_barrier" ::: "memory");

  // GITER(T): load A(T+8) into slot T&7; load B(T+4) into temps;
  // LDS-write tile T+1 (slot (T+1)&7, loaded 7 iters ago) to buf (T+1)&3;
  // barrier; compute tile T from buf T&3 with B pair T&3; commit B temps.
#define GITER(T, SNEW, SWR, BK0, BK1)                                 \
  {                                                                   \
    if ((T) < 24) SNEW = loadA((T) + 8);                              \
    short8 nb0 = BK0, nb1 = BK1;                                      \
    if ((T) < 28) { nb0 = loadB((T) + 4, 0); nb1 = loadB((T) + 4, 1); } \
    writeA(SWR, ((T) + 1) & 3);                                       \
    asm volatile("s_waitcnt lgkmcnt(0)\n\ts_barrier" ::: "memory");   \
    compute((T) & 3, BK0, BK1);                                       \
    BK0 = nb0; BK1 = nb1;                                             \
  }

#pragma unroll 1
  for (int t8 = 0; t8 < 32; t8 += 8) {
    GITER(t8 + 0, sA0, sA1, b0k0, b0k1);
    GITER(t8 + 1, sA1, sA2, b1k0, b1k1);
    GITER(t8 + 2, sA2, sA3, b2k0, b2k1);
    GITER(t8 + 3, sA3, sA4, b3k0, b3k1);
    GITER(t8 + 4, sA4, sA5, b0k0, b0k1);
    GITER(t8 + 5, sA5, sA6, b1k0, b1k1);
    GITER(t8 + 6, sA6, sA7, b2k0, b2k1);
    GITER(t8 + 7, sA7, sA0, b3k0, b3k1);
  }
#undef GITER

  const float bv = bias[oc];
  const int rbase = (ln >> 4) << 2;
#pragma unroll
  for (int m = 0; m < 2; ++m) {
    f32x4 dn = *(const f32x4*)(dnorm + (size_t)bb * NN + m0 + m * 16 + rbase);
#pragma unroll
    for (int rr = 0; rr < 4; ++rr)
      out[(size_t)(bb * NN + m0 + m * 16 + rbase + rr) * DD + oc] = acc[m][rr] * dn[rr] + bv;
  }
}

extern "C" void kernel_launch(void* const* d_in, const int* in_sizes, int n_in,
                              void* d_out, int out_size, void* d_ws, size_t ws_size,
                              hipStream_t stream) {
  (void)in_sizes; (void)n_in; (void)out_size; (void)ws_size;
  const float* x = (const float*)d_in[0];
  const float* adj = (const float*)d_in[1];
  const float* W = (const float*)d_in[2];
  const float* bias = (const float*)d_in[3];
  float* out = (float*)d_out;

  char* ws = (char*)d_ws;
  float* dnorm = (float*)ws;             // 64 KB
  short* yT = (short*)(ws + (1 << 16));  // 4 MB

  k_degree<<<4096, 256, 0, stream>>>(adj, dnorm);
  k_y<<<256, 256, 0, stream>>>(x, W, dnorm, yT);
  k_gemm<<<512, 512, 0, stream>>>(adj, yT, dnorm, bias, out);
}